// Round 11
// baseline (197.701 us; speedup 1.0000x reference)
//
#include <hip/hip_runtime.h>
#include <stdint.h>

typedef __attribute__((ext_vector_type(8))) short short8;
typedef __attribute__((ext_vector_type(4))) float f32x4;

typedef const unsigned int __attribute__((address_space(1))) gu32;
typedef unsigned int __attribute__((address_space(3))) lu32;

__device__ __forceinline__ float bf2f(unsigned short u) {
  union { unsigned int i; float f; } v; v.i = ((unsigned int)u) << 16; return v.f;
}
__device__ __forceinline__ unsigned short f2bf(float f) {
  union { float f; unsigned int i; } v; v.f = f;
  unsigned int r = v.i + 0x7FFFu + ((v.i >> 16) & 1u);
  return (unsigned short)(r >> 16);
}
__device__ __forceinline__ float fexp2(float x) {
  float r; asm("v_exp_f32 %0, %1" : "=v"(r) : "v"(x)); return r;
}
__device__ __forceinline__ unsigned int cvtpk(float lo, float hi) {
  unsigned int r;
  asm("v_cvt_pk_bf16_f32 %0, %1, %2" : "=v"(r) : "v"(lo), "v"(hi));
  return r;
}

// ------- fused: cast X fp32->bf16 (blocks 0..8191) + fold LoRA (8192..) ---
__global__ __launch_bounds__(256) void prep_in(
    const float* __restrict__ X, unsigned short* __restrict__ Xb,
    const float* __restrict__ Wq, const float* __restrict__ Wk,
    const float* __restrict__ Wv, const float* __restrict__ Wo,
    const float* __restrict__ qd, const float* __restrict__ qu,
    const float* __restrict__ kd, const float* __restrict__ ku,
    const float* __restrict__ vd, const float* __restrict__ vu,
    const float* __restrict__ od, const float* __restrict__ ou,
    unsigned short* __restrict__ Wqkv, unsigned short* __restrict__ Wob)
{
  if (blockIdx.x < 8192) {
    int i = (blockIdx.x * 256 + threadIdx.x) * 4;
    float4 v = *(const float4*)&X[i];
    unsigned long long pk = (unsigned long long)f2bf(v.x) |
                            ((unsigned long long)f2bf(v.y) << 16) |
                            ((unsigned long long)f2bf(v.z) << 32) |
                            ((unsigned long long)f2bf(v.w) << 48);
    *(unsigned long long*)&Xb[i] = pk;
    return;
  }
  int idx = (blockIdx.x - 8192) * 256 + threadIdx.x;
  int sel = idx >> 18;
  int rem = (idx & 0x3FFFF) * 4;
  int o = rem >> 10, c = rem & 1023;
  const float *W, *up, *dn;
  if (sel == 0)      { W = Wq; up = qu; dn = qd; }
  else if (sel == 1) { W = Wk; up = ku; dn = kd; }
  else if (sel == 2) { W = Wv; up = vu; dn = vd; }
  else               { W = Wo; up = ou; dn = od; }
  float4 wv = *(const float4*)&W[rem];
  float a0 = wv.x, a1 = wv.y, a2 = wv.z, a3 = wv.w;
  #pragma unroll
  for (int r = 0; r < 4; r++) {
    float u = up[o * 4 + r];
    float4 dv = *(const float4*)&dn[r * 1024 + c];
    a0 += u * dv.x; a1 += u * dv.y; a2 += u * dv.z; a3 += u * dv.w;
  }
  unsigned long long pk = (unsigned long long)f2bf(a0) |
                          ((unsigned long long)f2bf(a1) << 16) |
                          ((unsigned long long)f2bf(a2) << 32) |
                          ((unsigned long long)f2bf(a3) << 48);
  if (sel < 3) *(unsigned long long*)&Wqkv[sel * 1048576 + rem] = pk;
  else         *(unsigned long long*)&Wob[rem] = pk;
}

// ========== QKV GEMM: 256x256 tile, BK=64, 8 waves, 8-phase schedule =====
// T3+T4 port: 2 K-tiles/iter, 1 half-tile staged/phase, counted vmcnt(4) at
// phases 4 & 8 only. LDS halves swizzled with the attn-proven XOR (chunk8 ^=
// row&7), applied on BOTH sides: pre-swizzled per-lane global source +
// swizzled ds_read (rule #21). Wave = 128x64 out (8x4 16x16 frags).
// Epilogue routes Q->QKV, K->Kswz(swizzled), V->VTs(transposed+swizzled).
__global__ __launch_bounds__(512, 2) void gemm_qkv8(
    const unsigned short* __restrict__ A, const unsigned short* __restrict__ B,
    unsigned short* __restrict__ Cb, unsigned short* __restrict__ Kswz,
    unsigned short* __restrict__ VTs)
{
  const int K = 1024;
  __shared__ unsigned short smA[2][2][128 * 64];
  __shared__ unsigned short smB[2][2][128 * 64];
  const int tid = threadIdx.x;
  const int w = tid >> 6, lane = tid & 63;
  const int g = lane >> 4, lr = lane & 15;
  const int wm = w >> 2, wn = w & 3;
  const int m0 = blockIdx.y * 256, n0 = blockIdx.x * 256;
  const int l8 = lane >> 3;                 // 0..7
  const int c8 = (lane & 7) ^ l8;           // pre-swizzled source chunk
  const unsigned short* gA = A + (size_t)(m0 + w * 16 + l8) * K + c8 * 8;
  const unsigned short* gB = B + (size_t)(n0 + w * 16 + l8) * K + c8 * 8;
  const int ldsOff = w * 1024;              // shorts: w*16 rows * 64

  f32x4 acc[8][4] = {};
  short8 af[4][2], bf0[2][2], bf1[2][2];

  // stage one half-tile (2 loads/wave): h 0,1 = A halves; 2,3 = B halves
  auto STG = [&](int d, int h, int kk) {
    if (h < 2) {
      const unsigned short* s = gA + (size_t)h * 128 * K + kk;
      __builtin_amdgcn_global_load_lds((gu32*)s, (lu32*)&smA[d][h][ldsOff], 16, 0, 0);
      __builtin_amdgcn_global_load_lds((gu32*)(s + (size_t)8 * K), (lu32*)&smA[d][h][ldsOff + 512], 16, 0, 0);
    } else {
      const unsigned short* s = gB + (size_t)(h - 2) * 128 * K + kk;
      __builtin_amdgcn_global_load_lds((gu32*)s, (lu32*)&smB[d][h - 2][ldsOff], 16, 0, 0);
      __builtin_amdgcn_global_load_lds((gu32*)(s + (size_t)8 * K), (lu32*)&smB[d][h - 2][ldsOff + 512], 16, 0, 0);
    }
  };
  auto LDA = [&](int d, int h2) {
    #pragma unroll
    for (int mi2 = 0; mi2 < 4; mi2++)
      #pragma unroll
      for (int ks = 0; ks < 2; ks++) {
        int row = h2 * 64 + mi2 * 16 + lr;
        af[mi2][ks] = *(const short8*)&smA[d][wm][row * 64 + (((g + ks * 4) ^ (lr & 7))) * 8];
      }
  };
  auto LDB = [&](int d, int n2, short8 bf[2][2]) {
    #pragma unroll
    for (int ni2 = 0; ni2 < 2; ni2++)
      #pragma unroll
      for (int ks = 0; ks < 2; ks++) {
        int row = (wn & 1) * 64 + (n2 * 2 + ni2) * 16 + lr;
        bf[ni2][ks] = *(const short8*)&smB[d][wn >> 1][row * 64 + (((g + ks * 4) ^ (lr & 7))) * 8];
      }
  };
  auto MM = [&](int h2, int n2, short8 bf[2][2]) {
    __builtin_amdgcn_s_setprio(1);
    #pragma unroll
    for (int mi2 = 0; mi2 < 4; mi2++)
      #pragma unroll
      for (int ni2 = 0; ni2 < 2; ni2++)
        #pragma unroll
        for (int ks = 0; ks < 2; ks++)
          acc[h2 * 4 + mi2][n2 * 2 + ni2] =
              __builtin_amdgcn_mfma_f32_16x16x32_bf16(af[mi2][ks], bf[ni2][ks],
                                                      acc[h2 * 4 + mi2][n2 * 2 + ni2], 0, 0, 0);
    __builtin_amdgcn_s_setprio(0);
  };

#define PH_SYNC() do { \
    __builtin_amdgcn_sched_barrier(0); \
    __builtin_amdgcn_s_barrier(); \
    asm volatile("s_waitcnt lgkmcnt(0)" ::: "memory"); \
    __builtin_amdgcn_sched_barrier(0); } while (0)
#define PH_END() do { \
    __builtin_amdgcn_sched_barrier(0); \
    __builtin_amdgcn_s_barrier(); } while (0)

  // prologue: dbuf0 <- ktile0 (B0,B1,A0,A1); dbuf1.B <- ktile1
  STG(0, 2, 0); STG(0, 3, 0); STG(0, 0, 0); STG(0, 1, 0);
  STG(1, 2, 64); STG(1, 3, 64);
  asm volatile("s_waitcnt vmcnt(4)" ::: "memory");      // dbuf0 landed
  __builtin_amdgcn_sched_barrier(0);
  __builtin_amdgcn_s_barrier();
  __builtin_amdgcn_sched_barrier(0);

  for (int i = 0; i < 8; ++i) {
    int kA1 = ((2 * i + 1) & 15) * 64;   // dbuf1 A halves, ktile 2i+1
    int k02 = ((2 * i + 2) & 15) * 64;   // dbuf0 refill,  ktile 2i+2
    int k13 = ((2 * i + 3) & 15) * 64;   // dbuf1 B halves, ktile 2i+3
    // --- K-tile 2i (dbuf0) ---
    LDA(0, 0); LDB(0, 0, bf0); STG(1, 0, kA1);          // p1 (12 reads)
    PH_SYNC(); MM(0, 0, bf0); PH_END();
    LDB(0, 1, bf1); STG(1, 1, kA1);                     // p2
    PH_SYNC(); MM(0, 1, bf1); PH_END();
    LDA(0, 1); STG(0, 2, k02);                          // p3
    PH_SYNC(); MM(1, 0, bf0); PH_END();
    STG(0, 3, k02);                                     // p4
    asm volatile("s_waitcnt vmcnt(4)" ::: "memory");    // dbuf1 A+B landed
    PH_SYNC(); MM(1, 1, bf1); PH_END();
    // --- K-tile 2i+1 (dbuf1) ---
    LDA(1, 0); LDB(1, 0, bf0); STG(0, 0, k02);          // p5
    PH_SYNC(); MM(0, 0, bf0); PH_END();
    LDB(1, 1, bf1); STG(0, 1, k02);                     // p6
    PH_SYNC(); MM(0, 1, bf1); PH_END();
    LDA(1, 1); STG(1, 2, k13);                          // p7
    PH_SYNC(); MM(1, 0, bf0); PH_END();
    STG(1, 3, k13);                                     // p8
    asm volatile("s_waitcnt vmcnt(4)" ::: "memory");    // dbuf0 refill landed
    PH_SYNC(); MM(1, 1, bf1); PH_END();
  }
  asm volatile("s_waitcnt vmcnt(0)" ::: "memory");      // drain before exit
  __builtin_amdgcn_sched_barrier(0);

#undef PH_SYNC
#undef PH_END

  // epilogue: route by column section (whole block is in one section)
  const int sec = (n0 >> 10);
  #pragma unroll
  for (int mi = 0; mi < 8; mi++) {
    #pragma unroll
    for (int ni = 0; ni < 4; ni++) {
      int col = n0 + wn * 64 + ni * 16 + lr;
      #pragma unroll
      for (int j = 0; j < 4; j++) {
        int row = m0 + wm * 128 + mi * 16 + g * 4 + j;
        unsigned short ov = f2bf(acc[mi][ni][j]);
        int b_ = row >> 11, s = row & 2047;
        if (sec == 0) {
          Cb[(size_t)row * 3072 + col] = ov;                       // Q
        } else if (sec == 1) {
          int ck = col - 1024, h = ck >> 6, d = ck & 63;           // K -> Kswz
          Kswz[((size_t)(b_ * 16 + h) * 2048 + s) * 64 + (d ^ ((s & 7) << 3))] = ov;
        } else {
          int ck = col - 2048, h = ck >> 6, d = ck & 63;           // V -> VTs^T
          VTs[((size_t)((b_ * 16 + h) * 64 + d)) * 2048 +
              (s & ~63) + ((s & 63) ^ ((d & 7) << 3))] = ov;
        }
      }
    }
  }
}

// ---------------- bf16 GEMM (o-proj), 128x128, 3-slot counted vmcnt ------
__global__ __launch_bounds__(256) void gemm_o(
    const unsigned short* __restrict__ A, const unsigned short* __restrict__ B,
    float* __restrict__ Cf, const float* __restrict__ bias, int M, int N, int K)
{
  __shared__ unsigned short smA[3][128 * 32];
  __shared__ unsigned short smB[3][128 * 32];
  const int tid = threadIdx.x;
  const int w = tid >> 6, lane = tid & 63;
  const int g = lane >> 4, lr = lane & 15;
  const int m0 = blockIdx.y * 128, n0 = blockIdx.x * 128;
  const int srow = lane >> 2;
  const int scol = (lane & 3) * 8;
  const unsigned short* gA = A + (size_t)(m0 + w * 16 + srow) * K + scol;
  const unsigned short* gB = B + (size_t)(n0 + w * 16 + srow) * K + scol;
  f32x4 acc[4][4] = {};
  const int wr = (w >> 1) * 64, wc = (w & 1) * 64;

  auto stage = [&](int buf, int k0) {
    #pragma unroll
    for (int i = 0; i < 2; i++) {
      __builtin_amdgcn_global_load_lds((gu32*)(gA + (size_t)i * 64 * K + k0),
          (lu32*)&smA[buf][(i * 64 + w * 16) * 32], 16, 0, 0);
      __builtin_amdgcn_global_load_lds((gu32*)(gB + (size_t)i * 64 * K + k0),
          (lu32*)&smB[buf][(i * 64 + w * 16) * 32], 16, 0, 0);
    }
  };
  auto compute = [&](int buf) {
    short8 a[4], b[4];
    #pragma unroll
    for (int mi = 0; mi < 4; mi++) a[mi] = *(const short8*)&smA[buf][(wr + mi * 16 + lr) * 32 + g * 8];
    #pragma unroll
    for (int ni = 0; ni < 4; ni++) b[ni] = *(const short8*)&smB[buf][(wc + ni * 16 + lr) * 32 + g * 8];
    #pragma unroll
    for (int mi = 0; mi < 4; mi++)
      #pragma unroll
      for (int ni = 0; ni < 4; ni++)
        acc[mi][ni] = __builtin_amdgcn_mfma_f32_16x16x32_bf16(a[mi], b[ni], acc[mi][ni], 0, 0, 0);
  };

  const int nt = K / 32;
  stage(0, 0);
  stage(1, 32);
  int cur = 0;
  for (int t = 0; t + 2 < nt; ++t) {
    asm volatile("s_waitcnt vmcnt(4)" ::: "memory");
    __builtin_amdgcn_sched_barrier(0);
    __builtin_amdgcn_s_barrier();
    __builtin_amdgcn_sched_barrier(0);
    int nb = (cur == 0) ? 2 : cur - 1;
    stage(nb, (t + 2) * 32);
    compute(cur);
    asm volatile("s_waitcnt lgkmcnt(0)" ::: "memory");
    __builtin_amdgcn_sched_barrier(0);
    cur = (cur == 2) ? 0 : cur + 1;
  }
  asm volatile("s_waitcnt vmcnt(4)" ::: "memory");
  __builtin_amdgcn_sched_barrier(0);
  __builtin_amdgcn_s_barrier();
  __builtin_amdgcn_sched_barrier(0);
  compute(cur);
  asm volatile("s_waitcnt lgkmcnt(0)" ::: "memory");
  __builtin_amdgcn_sched_barrier(0);
  cur = (cur == 2) ? 0 : cur + 1;
  asm volatile("s_waitcnt vmcnt(0)" ::: "memory");
  __builtin_amdgcn_sched_barrier(0);
  __builtin_amdgcn_s_barrier();
  __builtin_amdgcn_sched_barrier(0);
  compute(cur);

  #pragma unroll
  for (int mi = 0; mi < 4; mi++) {
    #pragma unroll
    for (int ni = 0; ni < 4; ni++) {
      int col = n0 + wc + ni * 16 + lr;
      #pragma unroll
      for (int j = 0; j < 4; j++) {
        int row = m0 + wr + mi * 16 + g * 4 + j;
        Cf[(size_t)row * N + col] = acc[mi][ni][j] + bias[col];
      }
    }
  }
}

// ---------------- flash attention, bf16, swapped QK^T (16x16) ------------
__global__ __launch_bounds__(512, 4) void attn(
    const unsigned short* __restrict__ QKV,
    const unsigned short* __restrict__ Kswz,
    const unsigned short* __restrict__ VTs,
    unsigned short* __restrict__ O)
{
  __shared__ unsigned short smK[3][64 * 64];
  __shared__ unsigned short smV[3][64 * 64];
  __shared__ unsigned short smP[8][32 * 64];
  int bh = blockIdx.x, qb = blockIdx.y;
  int b = bh >> 4, h = bh & 15;
  int tid = threadIdx.x, w = tid >> 6, lane = tid & 63;
  int g = lane >> 4, lr = lane & 15;
  int q0 = qb * 256 + w * 32;
  const size_t kbse = (size_t)bh * 2048 * 64;
  const size_t vbse = (size_t)bh * 64 * 2048;
  const int srow8 = lane >> 3;
  const int sc8 = (lane & 7) * 8;

  auto stage = [&](int buf, int n0) {
    const unsigned short* gk = &Kswz[kbse + (size_t)(n0 + w * 8 + srow8) * 64 + sc8];
    __builtin_amdgcn_global_load_lds((gu32*)gk, (lu32*)&smK[buf][(w * 8) * 64], 16, 0, 0);
    const unsigned short* gv = &VTs[vbse + (size_t)(w * 8 + srow8) * 2048 + n0 + sc8];
    __builtin_amdgcn_global_load_lds((gu32*)gv, (lu32*)&smV[buf][(w * 8) * 64], 16, 0, 0);
  };

  const float SC = 0.125f * 1.44269504f;
  short8 bq[2][2];
  #pragma unroll
  for (int qf = 0; qf < 2; qf++)
    #pragma unroll
    for (int ks = 0; ks < 2; ks++) {
      short8 v = *(const short8*)&QKV[(size_t)(b * 2048 + q0 + qf * 16 + lr) * 3072 +
                                      h * 64 + ks * 32 + g * 8];
      #pragma unroll
      for (int j = 0; j < 4; j++) {
        float f0 = bf2f((unsigned short)v[2 * j]) * SC;
        float f1 = bf2f((unsigned short)v[2 * j + 1]) * SC;
        ((unsigned int*)&v)[j] = cvtpk(f0, f1);
      }
      bq[qf][ks] = v;
    }

  short8 vones;
  #pragma unroll
  for (int j = 0; j < 8; j++) vones[j] = (short)0x3F80;

  f32x4 acc_o[2][4] = {};
  f32x4 acc_l[2] = {};

  asm volatile("s_waitcnt vmcnt(0)" ::: "memory");
  __builtin_amdgcn_sched_barrier(0);
  stage(0, 0);
  stage(1, 64);

  auto compute = [&](int buf) {
    const unsigned short* K_ = smK[buf];
    const unsigned short* V_ = smV[buf];
    f32x4 s[4][2] = {};
    __builtin_amdgcn_s_setprio(1);
    #pragma unroll
    for (int nf = 0; nf < 4; nf++) {
      int row = nf * 16 + lr;
      #pragma unroll
      for (int ks = 0; ks < 2; ks++) {
        int eo = (ks * 64 + g * 16) ^ ((row & 7) << 4);
        short8 ak = *(const short8*)&K_[row * 64 + (eo >> 1)];
        #pragma unroll
        for (int qf = 0; qf < 2; qf++)
          s[nf][qf] = __builtin_amdgcn_mfma_f32_16x16x32_bf16(ak, bq[qf][ks], s[nf][qf], 0, 0, 0);
      }
    }
    __builtin_amdgcn_s_setprio(0);

    #pragma unroll
    for (int qf = 0; qf < 2; qf++) {
      int q = qf * 16 + lr;
      #pragma unroll
      for (int nf = 0; nf < 4; nf++) {
        float p0 = fexp2(s[nf][qf][0]);
        float p1 = fexp2(s[nf][qf][1]);
        float p2 = fexp2(s[nf][qf][2]);
        float p3 = fexp2(s[nf][qf][3]);
        uint2 pw;
        pw.x = cvtpk(p0, p1);
        pw.y = cvtpk(p2, p3);
        int eo = ((nf * 16 + g * 4) * 2) ^ ((q & 7) << 4);
        *(uint2*)&smP[w][q * 64 + (eo >> 1)] = pw;
      }
    }

    __builtin_amdgcn_s_setprio(1);
    #pragma unroll
    for (int ks = 0; ks < 2; ks++) {
      short8 ap[2];
      #pragma unroll
      for (int mq = 0; mq < 2; mq++) {
        int q = mq * 16 + lr;
        int eo = (ks * 64 + g * 16) ^ ((q & 7) << 4);
        ap[mq] = *(const short8*)&smP[w][q * 64 + (eo >> 1)];
        acc_l[mq] = __builtin_amdgcn_mfma_f32_16x16x32_bf16(ap[mq], vones, acc_l[mq], 0, 0, 0);
      }
      #pragma unroll
      for (int df = 0; df < 4; df++) {
        int d = df * 16 + lr;
        int eo = (ks * 64 + g * 16) ^ ((d & 7) << 4);
        short8 bv = *(const short8*)&V_[d * 64 + (eo >> 1)];
        #pragma unroll
        for (int mq = 0; mq < 2; mq++)
          acc_o[mq][df] = __builtin_amdgcn_mfma_f32_16x16x32_bf16(ap[mq], bv, acc_o[mq][df], 0, 0, 0);
      }
    }
    __builtin_amdgcn_s_setprio(0);
  };

  int cur = 0;
  for (int t = 0; t + 2 < 32; ++t) {
    asm volatile("s_waitcnt vmcnt(2)" ::: "memory");
    __builtin_amdgcn_sched_barrier(0);
    __builtin_amdgcn_s_barrier();
    __builtin_amdgcn_sched_barrier(0);
    int nb = (cur == 0) ? 2 : cur - 1;
    stage(nb, (t + 2) * 64);
    compute(cur);
    asm volatile("s_waitcnt lgkmcnt(0)" ::: "memory");
    __builtin_amdgcn_sched_barrier(0);
    cur = (cur == 2) ? 0 : cur + 1;
  }
  asm volatile("s_waitcnt vmcnt(2)" ::: "memory");
  __builtin_amdgcn_sched_barrier(0);
  __builtin_amdgcn_s_barrier();
  __builtin_amdgcn_sched_barrier(0);
  compute(cur);
  asm volatile("s_waitcnt lgkmcnt(0)" ::: "memory");
  __builtin_amdgcn_sched_barrier(0);
  cur = (cur == 2) ? 0 : cur + 1;
  asm volatile("s_waitcnt vmcnt(0)" ::: "memory");
  __builtin_amdgcn_sched_barrier(0);
  __builtin_amdgcn_s_barrier();
  __builtin_amdgcn_sched_barrier(0);
  compute(cur);

  #pragma unroll
  for (int mq = 0; mq < 2; mq++)
    #pragma unroll
    for (int j = 0; j < 4; j++) {
      float inv = 1.0f / acc_l[mq][j];
      #pragma unroll
      for (int df = 0; df < 4; df++) {
        int row = b * 2048 + q0 + mq * 16 + g * 4 + j;
        int col = h * 64 + df * 16 + lr;
        O[(size_t)row * 1024 + col] = f2bf(acc_o[mq][df][j] * inv);
      }
    }
}

// -------------------------------------------------------------------------
extern "C" void kernel_launch(void* const* d_in, const int* in_sizes, int n_in,
                              void* d_out, int out_size, void* d_ws, size_t ws_size,
                              hipStream_t stream) {
  const float* X  = (const float*)d_in[0];
  const float* Wq = (const float*)d_in[1];
  const float* Wk = (const float*)d_in[2];
  const float* Wv = (const float*)d_in[3];
  const float* Wo = (const float*)d_in[4];
  const float* bo = (const float*)d_in[5];
  const float* qd = (const float*)d_in[6];
  const float* qu = (const float*)d_in[7];
  const float* kd = (const float*)d_in[8];
  const float* ku = (const float*)d_in[9];
  const float* vd = (const float*)d_in[10];
  const float* vu = (const float*)d_in[11];
  const float* od = (const float*)d_in[12];
  const float* ou = (const float*)d_in[13];

  char* ws = (char*)d_ws;
  unsigned short* Wqkv = (unsigned short*)(ws);                       // 6,291,456 B
  unsigned short* Wob  = (unsigned short*)(ws + 6291456);             // 2,097,152 B
  unsigned short* Xb   = (unsigned short*)(ws + 8388608);             // 16,777,216 B (reused as attn out)
  unsigned short* QKV  = (unsigned short*)(ws + 25165824);            // 50,331,648 B (Q section live)
  unsigned short* Kswz = (unsigned short*)(ws + 75497472);            // 16,777,216 B
  unsigned short* VTs  = (unsigned short*)(ws + 92274688);            // 16,777,216 B

  prep_in<<<12288, 256, 0, stream>>>(X, Xb, Wq, Wk, Wv, Wo, qd, qu, kd, ku,
                                     vd, vu, od, ou, Wqkv, Wob);
  gemm_qkv8<<<dim3(12, 32), 512, 0, stream>>>(Xb, Wqkv, QKV, Kswz, VTs);
  attn<<<dim3(64, 8), 512, 0, stream>>>(QKV, Kswz, VTs, Xb);
  gemm_o<<<dim3(8, 64), 256, 0, stream>>>(Xb, Wob, (float*)d_out, bo,
                                          8192, 1024, 1024);
}

// Round 12
// 191.603 us; speedup vs baseline: 1.0318x; 1.0318x over previous
//
#include <hip/hip_runtime.h>
#include <stdint.h>

typedef __attribute__((ext_vector_type(8))) short short8;
typedef __attribute__((ext_vector_type(4))) float f32x4;

typedef const unsigned int __attribute__((address_space(1))) gu32;
typedef unsigned int __attribute__((address_space(3))) lu32;

__device__ __forceinline__ float bf2f(unsigned short u) {
  union { unsigned int i; float f; } v; v.i = ((unsigned int)u) << 16; return v.f;
}
__device__ __forceinline__ unsigned short f2bf(float f) {
  union { float f; unsigned int i; } v; v.f = f;
  unsigned int r = v.i + 0x7FFFu + ((v.i >> 16) & 1u);
  return (unsigned short)(r >> 16);
}
__device__ __forceinline__ float fexp2(float x) {
  float r; asm("v_exp_f32 %0, %1" : "=v"(r) : "v"(x)); return r;
}
__device__ __forceinline__ unsigned int cvtpk(float lo, float hi) {
  unsigned int r;
  asm("v_cvt_pk_bf16_f32 %0, %1, %2" : "=v"(r) : "v"(lo), "v"(hi));
  return r;
}

// ------- fused: cast X fp32->bf16 (blocks 0..8191) + fold LoRA (8192..) ---
__global__ __launch_bounds__(256) void prep_in(
    const float* __restrict__ X, unsigned short* __restrict__ Xb,
    const float* __restrict__ Wq, const float* __restrict__ Wk,
    const float* __restrict__ Wv, const float* __restrict__ Wo,
    const float* __restrict__ qd, const float* __restrict__ qu,
    const float* __restrict__ kd, const float* __restrict__ ku,
    const float* __restrict__ vd, const float* __restrict__ vu,
    const float* __restrict__ od, const float* __restrict__ ou,
    unsigned short* __restrict__ Wqkv, unsigned short* __restrict__ Wob)
{
  if (blockIdx.x < 8192) {
    int i = (blockIdx.x * 256 + threadIdx.x) * 4;
    float4 v = *(const float4*)&X[i];
    unsigned long long pk = (unsigned long long)f2bf(v.x) |
                            ((unsigned long long)f2bf(v.y) << 16) |
                            ((unsigned long long)f2bf(v.z) << 32) |
                            ((unsigned long long)f2bf(v.w) << 48);
    *(unsigned long long*)&Xb[i] = pk;
    return;
  }
  int idx = (blockIdx.x - 8192) * 256 + threadIdx.x;
  int sel = idx >> 18;
  int rem = (idx & 0x3FFFF) * 4;
  int o = rem >> 10, c = rem & 1023;
  const float *W, *up, *dn;
  if (sel == 0)      { W = Wq; up = qu; dn = qd; }
  else if (sel == 1) { W = Wk; up = ku; dn = kd; }
  else if (sel == 2) { W = Wv; up = vu; dn = vd; }
  else               { W = Wo; up = ou; dn = od; }
  float4 wv = *(const float4*)&W[rem];
  float a0 = wv.x, a1 = wv.y, a2 = wv.z, a3 = wv.w;
  #pragma unroll
  for (int r = 0; r < 4; r++) {
    float u = up[o * 4 + r];
    float4 dv = *(const float4*)&dn[r * 1024 + c];
    a0 += u * dv.x; a1 += u * dv.y; a2 += u * dv.z; a3 += u * dv.w;
  }
  unsigned long long pk = (unsigned long long)f2bf(a0) |
                          ((unsigned long long)f2bf(a1) << 16) |
                          ((unsigned long long)f2bf(a2) << 32) |
                          ((unsigned long long)f2bf(a3) << 48);
  if (sel < 3) *(unsigned long long*)&Wqkv[sel * 1048576 + rem] = pk;
  else         *(unsigned long long*)&Wob[rem] = pk;
}

// ---------------- bf16 GEMM, B^T input (C[m,n] = sum_k A[m,k]*B[n,k]) ----
// 128x128 tile, BK=32, 4 waves, 256 thr (proven structure). 3-slot LDS
// rotation, counted vmcnt(4), vmcnt before barrier, lgkmcnt(0) read-pin.
// OUTF=0 (QKV): Q cols [0,1024) and V cols [2048,3072) -> QKV linear
// (full-line coalesced stores); K cols [1024,2048) -> Kswz swizzled
// (cheap: XOR stays within the 128B row). V transpose done by prep_v.
// OUTF=1: fp32 out + bias.
template <int OUTF>
__global__ __launch_bounds__(256) void gemm_bt(
    const unsigned short* __restrict__ A, const unsigned short* __restrict__ B,
    unsigned short* __restrict__ Cb, float* __restrict__ Cf,
    const float* __restrict__ bias, unsigned short* __restrict__ Kswz,
    int M, int N, int K)
{
  __shared__ unsigned short smA[3][128 * 32];
  __shared__ unsigned short smB[3][128 * 32];
  const int tid = threadIdx.x;
  const int w = tid >> 6, lane = tid & 63;
  const int g = lane >> 4, lr = lane & 15;
  const int m0 = blockIdx.y * 128, n0 = blockIdx.x * 128;
  const int srow = lane >> 2;
  const int scol = (lane & 3) * 8;
  const unsigned short* gA = A + (size_t)(m0 + w * 16 + srow) * K + scol;
  const unsigned short* gB = B + (size_t)(n0 + w * 16 + srow) * K + scol;
  f32x4 acc[4][4] = {};
  const int wr = (w >> 1) * 64, wc = (w & 1) * 64;

  auto stage = [&](int buf, int k0) {
    #pragma unroll
    for (int i = 0; i < 2; i++) {
      __builtin_amdgcn_global_load_lds((gu32*)(gA + (size_t)i * 64 * K + k0),
          (lu32*)&smA[buf][(i * 64 + w * 16) * 32], 16, 0, 0);
      __builtin_amdgcn_global_load_lds((gu32*)(gB + (size_t)i * 64 * K + k0),
          (lu32*)&smB[buf][(i * 64 + w * 16) * 32], 16, 0, 0);
    }
  };
  auto compute = [&](int buf) {
    short8 a[4], b[4];
    #pragma unroll
    for (int mi = 0; mi < 4; mi++) a[mi] = *(const short8*)&smA[buf][(wr + mi * 16 + lr) * 32 + g * 8];
    #pragma unroll
    for (int ni = 0; ni < 4; ni++) b[ni] = *(const short8*)&smB[buf][(wc + ni * 16 + lr) * 32 + g * 8];
    #pragma unroll
    for (int mi = 0; mi < 4; mi++)
      #pragma unroll
      for (int ni = 0; ni < 4; ni++)
        acc[mi][ni] = __builtin_amdgcn_mfma_f32_16x16x32_bf16(a[mi], b[ni], acc[mi][ni], 0, 0, 0);
  };

  const int nt = K / 32;                 // >= 3
  stage(0, 0);
  stage(1, 32);
  int cur = 0;
  for (int t = 0; t + 2 < nt; ++t) {
    asm volatile("s_waitcnt vmcnt(4)" ::: "memory");   // stage(t) landed
    __builtin_amdgcn_sched_barrier(0);
    __builtin_amdgcn_s_barrier();
    __builtin_amdgcn_sched_barrier(0);
    int nb = (cur == 0) ? 2 : cur - 1;                 // (cur+2)%3
    stage(nb, (t + 2) * 32);
    compute(cur);
    asm volatile("s_waitcnt lgkmcnt(0)" ::: "memory"); // pin ds_reads before next barrier
    __builtin_amdgcn_sched_barrier(0);
    cur = (cur == 2) ? 0 : cur + 1;
  }
  asm volatile("s_waitcnt vmcnt(4)" ::: "memory");
  __builtin_amdgcn_sched_barrier(0);
  __builtin_amdgcn_s_barrier();
  __builtin_amdgcn_sched_barrier(0);
  compute(cur);
  asm volatile("s_waitcnt lgkmcnt(0)" ::: "memory");
  __builtin_amdgcn_sched_barrier(0);
  cur = (cur == 2) ? 0 : cur + 1;
  asm volatile("s_waitcnt vmcnt(0)" ::: "memory");
  __builtin_amdgcn_sched_barrier(0);
  __builtin_amdgcn_s_barrier();
  __builtin_amdgcn_sched_barrier(0);
  compute(cur);

  #pragma unroll
  for (int mi = 0; mi < 4; mi++) {
    #pragma unroll
    for (int ni = 0; ni < 4; ni++) {
      int col = n0 + wc + ni * 16 + lr;
      if (OUTF == 0) {
        int sec = col >> 10;           // uniform per ni (16-col block in one section)
        #pragma unroll
        for (int j = 0; j < 4; j++) {
          int row = m0 + wr + mi * 16 + g * 4 + j;
          unsigned short ov = f2bf(acc[mi][ni][j]);
          if (sec == 1) {
            int b_ = row >> 11, s = row & 2047;
            int ck = col - 1024, h = ck >> 6, d = ck & 63;           // K -> Kswz
            Kswz[((size_t)(b_ * 16 + h) * 2048 + s) * 64 + (d ^ ((s & 7) << 3))] = ov;
          } else {
            Cb[(size_t)row * 3072 + col] = ov;                       // Q, V linear
          }
        }
      } else {
        #pragma unroll
        for (int j = 0; j < 4; j++) {
          int row = m0 + wr + mi * 16 + g * 4 + j;
          Cf[(size_t)row * N + col] = acc[mi][ni][j] + bias[col];
        }
      }
    }
  }
}

// ---------------- prep: V transpose into swizzled VTs --------------------
// VTswz[bh][d][s_hi*64 + (s_lo ^ ((d&7)<<3))]  (green in R9)
__global__ __launch_bounds__(256) void prep_v(
    const unsigned short* __restrict__ QKV, unsigned short* __restrict__ VTs)
{
  __shared__ unsigned short vt[64 * 72];
  int bh = blockIdx.x;            // 64
  int st = blockIdx.y;            // 32
  int b = bh >> 4, h = bh & 15;
  int s0 = st * 64;
  int tid = threadIdx.x;
  #pragma unroll
  for (int i = 0; i < 2; i++) {
    int idx = tid + i * 256;      // 0..511
    int r = idx >> 3, gch = idx & 7;
    size_t rowg = (size_t)(b * 2048 + s0 + r) * 3072;
    short8 vv = *(const short8*)&QKV[rowg + 2048 + h * 64 + gch * 8];
    *(short8*)&vt[r * 72 + gch * 8] = vv;
  }
  __syncthreads();
  #pragma unroll
  for (int i = 0; i < 2; i++) {
    int idx = tid + i * 256;
    int d = idx >> 3, gp = idx & 7;
    int gs = gp ^ (d & 7);
    short8 o;
    #pragma unroll
    for (int j = 0; j < 8; j++) o[j] = (short)vt[(gs * 8 + j) * 72 + d];
    *(short8*)&VTs[(size_t)(bh * 64 + d) * 2048 + s0 + gp * 8] = o;
  }
}

// ---------------- flash attention, bf16, swapped QK^T (16x16) ------------
// grid: (64 bh, 8 q-blocks of 256) -- bh on blockIdx.x so all 8 q-blocks of
// one bh land on one XCD: K/V stays in that XCD's L2 (FETCH 139->24.6MB, R8).
// 8 waves; wave owns 32 q-rows. Fixed-max softmax; l via MFMA(ones);
// 3-slot K/V staging, counted vmcnt(2), vmcnt before barrier.
__global__ __launch_bounds__(512, 4) void attn(
    const unsigned short* __restrict__ QKV,
    const unsigned short* __restrict__ Kswz,
    const unsigned short* __restrict__ VTs,
    unsigned short* __restrict__ O)
{
  __shared__ unsigned short smK[3][64 * 64];
  __shared__ unsigned short smV[3][64 * 64];
  __shared__ unsigned short smP[8][32 * 64];
  int bh = blockIdx.x, qb = blockIdx.y;
  int b = bh >> 4, h = bh & 15;
  int tid = threadIdx.x, w = tid >> 6, lane = tid & 63;
  int g = lane >> 4, lr = lane & 15;
  int q0 = qb * 256 + w * 32;
  const size_t kbse = (size_t)bh * 2048 * 64;
  const size_t vbse = (size_t)bh * 64 * 2048;
  const int srow8 = lane >> 3;
  const int sc8 = (lane & 7) * 8;

  auto stage = [&](int buf, int n0) {
    const unsigned short* gk = &Kswz[kbse + (size_t)(n0 + w * 8 + srow8) * 64 + sc8];
    __builtin_amdgcn_global_load_lds((gu32*)gk, (lu32*)&smK[buf][(w * 8) * 64], 16, 0, 0);
    const unsigned short* gv = &VTs[vbse + (size_t)(w * 8 + srow8) * 2048 + n0 + sc8];
    __builtin_amdgcn_global_load_lds((gu32*)gv, (lu32*)&smV[buf][(w * 8) * 64], 16, 0, 0);
  };

  const float SC = 0.125f * 1.44269504f;
  short8 bq[2][2];
  #pragma unroll
  for (int qf = 0; qf < 2; qf++)
    #pragma unroll
    for (int ks = 0; ks < 2; ks++) {
      short8 v = *(const short8*)&QKV[(size_t)(b * 2048 + q0 + qf * 16 + lr) * 3072 +
                                      h * 64 + ks * 32 + g * 8];
      #pragma unroll
      for (int j = 0; j < 4; j++) {
        float f0 = bf2f((unsigned short)v[2 * j]) * SC;
        float f1 = bf2f((unsigned short)v[2 * j + 1]) * SC;
        ((unsigned int*)&v)[j] = cvtpk(f0, f1);
      }
      bq[qf][ks] = v;
    }

  short8 vones;
  #pragma unroll
  for (int j = 0; j < 8; j++) vones[j] = (short)0x3F80;

  f32x4 acc_o[2][4] = {};
  f32x4 acc_l[2] = {};

  asm volatile("s_waitcnt vmcnt(0)" ::: "memory");
  __builtin_amdgcn_sched_barrier(0);
  stage(0, 0);
  stage(1, 64);

  auto compute = [&](int buf) {
    const unsigned short* K_ = smK[buf];
    const unsigned short* V_ = smV[buf];
    f32x4 s[4][2] = {};
    __builtin_amdgcn_s_setprio(1);
    #pragma unroll
    for (int nf = 0; nf < 4; nf++) {
      int row = nf * 16 + lr;
      #pragma unroll
      for (int ks = 0; ks < 2; ks++) {
        int eo = (ks * 64 + g * 16) ^ ((row & 7) << 4);
        short8 ak = *(const short8*)&K_[row * 64 + (eo >> 1)];
        #pragma unroll
        for (int qf = 0; qf < 2; qf++)
          s[nf][qf] = __builtin_amdgcn_mfma_f32_16x16x32_bf16(ak, bq[qf][ks], s[nf][qf], 0, 0, 0);
      }
    }
    __builtin_amdgcn_s_setprio(0);

    #pragma unroll
    for (int qf = 0; qf < 2; qf++) {
      int q = qf * 16 + lr;
      #pragma unroll
      for (int nf = 0; nf < 4; nf++) {
        float p0 = fexp2(s[nf][qf][0]);
        float p1 = fexp2(s[nf][qf][1]);
        float p2 = fexp2(s[nf][qf][2]);
        float p3 = fexp2(s[nf][qf][3]);
        uint2 pw;
        pw.x = cvtpk(p0, p1);
        pw.y = cvtpk(p2, p3);
        int eo = ((nf * 16 + g * 4) * 2) ^ ((q & 7) << 4);
        *(uint2*)&smP[w][q * 64 + (eo >> 1)] = pw;
      }
    }

    __builtin_amdgcn_s_setprio(1);
    #pragma unroll
    for (int ks = 0; ks < 2; ks++) {
      short8 ap[2];
      #pragma unroll
      for (int mq = 0; mq < 2; mq++) {
        int q = mq * 16 + lr;
        int eo = (ks * 64 + g * 16) ^ ((q & 7) << 4);
        ap[mq] = *(const short8*)&smP[w][q * 64 + (eo >> 1)];
        acc_l[mq] = __builtin_amdgcn_mfma_f32_16x16x32_bf16(ap[mq], vones, acc_l[mq], 0, 0, 0);
      }
      #pragma unroll
      for (int df = 0; df < 4; df++) {
        int d = df * 16 + lr;
        int eo = (ks * 64 + g * 16) ^ ((d & 7) << 4);
        short8 bv = *(const short8*)&V_[d * 64 + (eo >> 1)];
        #pragma unroll
        for (int mq = 0; mq < 2; mq++)
          acc_o[mq][df] = __builtin_amdgcn_mfma_f32_16x16x32_bf16(ap[mq], bv, acc_o[mq][df], 0, 0, 0);
      }
    }
    __builtin_amdgcn_s_setprio(0);
  };

  int cur = 0;
  for (int t = 0; t + 2 < 32; ++t) {
    asm volatile("s_waitcnt vmcnt(2)" ::: "memory");
    __builtin_amdgcn_sched_barrier(0);
    __builtin_amdgcn_s_barrier();
    __builtin_amdgcn_sched_barrier(0);
    int nb = (cur == 0) ? 2 : cur - 1;
    stage(nb, (t + 2) * 64);
    compute(cur);
    asm volatile("s_waitcnt lgkmcnt(0)" ::: "memory");
    __builtin_amdgcn_sched_barrier(0);
    cur = (cur == 2) ? 0 : cur + 1;
  }
  asm volatile("s_waitcnt vmcnt(2)" ::: "memory");
  __builtin_amdgcn_sched_barrier(0);
  __builtin_amdgcn_s_barrier();
  __builtin_amdgcn_sched_barrier(0);
  compute(cur);
  asm volatile("s_waitcnt lgkmcnt(0)" ::: "memory");
  __builtin_amdgcn_sched_barrier(0);
  cur = (cur == 2) ? 0 : cur + 1;
  asm volatile("s_waitcnt vmcnt(0)" ::: "memory");
  __builtin_amdgcn_sched_barrier(0);
  __builtin_amdgcn_s_barrier();
  __builtin_amdgcn_sched_barrier(0);
  compute(cur);

  #pragma unroll
  for (int mq = 0; mq < 2; mq++)
    #pragma unroll
    for (int j = 0; j < 4; j++) {
      float inv = 1.0f / acc_l[mq][j];
      #pragma unroll
      for (int df = 0; df < 4; df++) {
        int row = b * 2048 + q0 + mq * 16 + g * 4 + j;
        int col = h * 64 + df * 16 + lr;
        O[(size_t)row * 1024 + col] = f2bf(acc_o[mq][df][j] * inv);
      }
    }
}

// -------------------------------------------------------------------------
extern "C" void kernel_launch(void* const* d_in, const int* in_sizes, int n_in,
                              void* d_out, int out_size, void* d_ws, size_t ws_size,
                              hipStream_t stream) {
  const float* X  = (const float*)d_in[0];
  const float* Wq = (const float*)d_in[1];
  const float* Wk = (const float*)d_in[2];
  const float* Wv = (const float*)d_in[3];
  const float* Wo = (const float*)d_in[4];
  const float* bo = (const float*)d_in[5];
  const float* qd = (const float*)d_in[6];
  const float* qu = (const float*)d_in[7];
  const float* kd = (const float*)d_in[8];
  const float* ku = (const float*)d_in[9];
  const float* vd = (const float*)d_in[10];
  const float* vu = (const float*)d_in[11];
  const float* od = (const float*)d_in[12];
  const float* ou = (const float*)d_in[13];

  char* ws = (char*)d_ws;
  unsigned short* Wqkv = (unsigned short*)(ws);                       // 6,291,456 B
  unsigned short* Wob  = (unsigned short*)(ws + 6291456);             // 2,097,152 B
  unsigned short* Xb   = (unsigned short*)(ws + 8388608);             // 16,777,216 B (reused as attn out)
  unsigned short* QKV  = (unsigned short*)(ws + 25165824);            // 50,331,648 B (Q+V live)
  unsigned short* Kswz = (unsigned short*)(ws + 75497472);            // 16,777,216 B
  unsigned short* VTs  = (unsigned short*)(ws + 92274688);            // 16,777,216 B

  prep_in<<<12288, 256, 0, stream>>>(X, Xb, Wq, Wk, Wv, Wo, qd, qu, kd, ku,
                                     vd, vu, od, ou, Wqkv, Wob);
  gemm_bt<0><<<dim3(24, 64), 256, 0, stream>>>(Xb, Wqkv, QKV, nullptr, nullptr,
                                               Kswz, 8192, 3072, 1024);
  prep_v<<<dim3(64, 32), 256, 0, stream>>>(QKV, VTs);
  attn<<<dim3(64, 8), 512, 0, stream>>>(QKV, Kswz, VTs, Xb);
  gemm_bt<1><<<dim3(8, 64), 256, 0, stream>>>(Xb, Wob, nullptr, (float*)d_out, bo,
                                              nullptr, 8192, 1024, 1024);
}

// Round 13
// 187.021 us; speedup vs baseline: 1.0571x; 1.0245x over previous
//
#include <hip/hip_runtime.h>
#include <stdint.h>

typedef __attribute__((ext_vector_type(8))) short short8;
typedef __attribute__((ext_vector_type(4))) float f32x4;

typedef const unsigned int __attribute__((address_space(1))) gu32;
typedef unsigned int __attribute__((address_space(3))) lu32;

__device__ __forceinline__ float bf2f(unsigned short u) {
  union { unsigned int i; float f; } v; v.i = ((unsigned int)u) << 16; return v.f;
}
__device__ __forceinline__ unsigned short f2bf(float f) {
  union { float f; unsigned int i; } v; v.f = f;
  unsigned int r = v.i + 0x7FFFu + ((v.i >> 16) & 1u);
  return (unsigned short)(r >> 16);
}
__device__ __forceinline__ float fexp2(float x) {
  float r; asm("v_exp_f32 %0, %1" : "=v"(r) : "v"(x)); return r;
}
__device__ __forceinline__ unsigned int cvtpk(float lo, float hi) {
  unsigned int r;
  asm("v_cvt_pk_bf16_f32 %0, %1, %2" : "=v"(r) : "v"(lo), "v"(hi));
  return r;
}

// ------- fused: cast X fp32->bf16 (blocks 0..8191) + fold LoRA (8192..) ---
__global__ __launch_bounds__(256) void prep_in(
    const float* __restrict__ X, unsigned short* __restrict__ Xb,
    const float* __restrict__ Wq, const float* __restrict__ Wk,
    const float* __restrict__ Wv, const float* __restrict__ Wo,
    const float* __restrict__ qd, const float* __restrict__ qu,
    const float* __restrict__ kd, const float* __restrict__ ku,
    const float* __restrict__ vd, const float* __restrict__ vu,
    const float* __restrict__ od, const float* __restrict__ ou,
    unsigned short* __restrict__ Wqkv, unsigned short* __restrict__ Wob)
{
  if (blockIdx.x < 8192) {
    int i = (blockIdx.x * 256 + threadIdx.x) * 4;
    float4 v = *(const float4*)&X[i];
    unsigned long long pk = (unsigned long long)f2bf(v.x) |
                            ((unsigned long long)f2bf(v.y) << 16) |
                            ((unsigned long long)f2bf(v.z) << 32) |
                            ((unsigned long long)f2bf(v.w) << 48);
    *(unsigned long long*)&Xb[i] = pk;
    return;
  }
  int idx = (blockIdx.x - 8192) * 256 + threadIdx.x;
  int sel = idx >> 18;
  int rem = (idx & 0x3FFFF) * 4;
  int o = rem >> 10, c = rem & 1023;
  const float *W, *up, *dn;
  if (sel == 0)      { W = Wq; up = qu; dn = qd; }
  else if (sel == 1) { W = Wk; up = ku; dn = kd; }
  else if (sel == 2) { W = Wv; up = vu; dn = vd; }
  else               { W = Wo; up = ou; dn = od; }
  float4 wv = *(const float4*)&W[rem];
  float a0 = wv.x, a1 = wv.y, a2 = wv.z, a3 = wv.w;
  #pragma unroll
  for (int r = 0; r < 4; r++) {
    float u = up[o * 4 + r];
    float4 dv = *(const float4*)&dn[r * 1024 + c];
    a0 += u * dv.x; a1 += u * dv.y; a2 += u * dv.z; a3 += u * dv.w;
  }
  unsigned long long pk = (unsigned long long)f2bf(a0) |
                          ((unsigned long long)f2bf(a1) << 16) |
                          ((unsigned long long)f2bf(a2) << 32) |
                          ((unsigned long long)f2bf(a3) << 48);
  if (sel < 3) *(unsigned long long*)&Wqkv[sel * 1048576 + rem] = pk;
  else         *(unsigned long long*)&Wob[rem] = pk;
}

// ---------------- bf16 GEMM, B^T input (C[m,n] = sum_k A[m,k]*B[n,k]) ----
// 128x128 tile, BK=32, 4 waves, 256 thr. 3-slot LDS rotation, counted
// vmcnt(4), vmcnt before barrier, lgkmcnt(0) read-pin.
// GRID: blockIdx.x = m-tile, blockIdx.y = n-tile. With round-robin id%8
// XCD placement, each XCD holds 8 A-panels (2MB, L2-resident, reused over
// all n) while B streams via L3 -- same mechanism as attn's R8 transpose.
// OUTF=0 (QKV): Q cols [0,1024) and V cols [2048,3072) -> QKV linear;
// K cols [1024,2048) -> Kswz swizzled. OUTF=1: fp32 out + bias.
template <int OUTF>
__global__ __launch_bounds__(256) void gemm_bt(
    const unsigned short* __restrict__ A, const unsigned short* __restrict__ B,
    unsigned short* __restrict__ Cb, float* __restrict__ Cf,
    const float* __restrict__ bias, unsigned short* __restrict__ Kswz,
    int M, int N, int K)
{
  __shared__ unsigned short smA[3][128 * 32];
  __shared__ unsigned short smB[3][128 * 32];
  const int tid = threadIdx.x;
  const int w = tid >> 6, lane = tid & 63;
  const int g = lane >> 4, lr = lane & 15;
  const int m0 = blockIdx.x * 128, n0 = blockIdx.y * 128;   // x=m, y=n
  const int srow = lane >> 2;
  const int scol = (lane & 3) * 8;
  const unsigned short* gA = A + (size_t)(m0 + w * 16 + srow) * K + scol;
  const unsigned short* gB = B + (size_t)(n0 + w * 16 + srow) * K + scol;
  f32x4 acc[4][4] = {};
  const int wr = (w >> 1) * 64, wc = (w & 1) * 64;

  auto stage = [&](int buf, int k0) {
    #pragma unroll
    for (int i = 0; i < 2; i++) {
      __builtin_amdgcn_global_load_lds((gu32*)(gA + (size_t)i * 64 * K + k0),
          (lu32*)&smA[buf][(i * 64 + w * 16) * 32], 16, 0, 0);
      __builtin_amdgcn_global_load_lds((gu32*)(gB + (size_t)i * 64 * K + k0),
          (lu32*)&smB[buf][(i * 64 + w * 16) * 32], 16, 0, 0);
    }
  };
  auto compute = [&](int buf) {
    short8 a[4], b[4];
    #pragma unroll
    for (int mi = 0; mi < 4; mi++) a[mi] = *(const short8*)&smA[buf][(wr + mi * 16 + lr) * 32 + g * 8];
    #pragma unroll
    for (int ni = 0; ni < 4; ni++) b[ni] = *(const short8*)&smB[buf][(wc + ni * 16 + lr) * 32 + g * 8];
    #pragma unroll
    for (int mi = 0; mi < 4; mi++)
      #pragma unroll
      for (int ni = 0; ni < 4; ni++)
        acc[mi][ni] = __builtin_amdgcn_mfma_f32_16x16x32_bf16(a[mi], b[ni], acc[mi][ni], 0, 0, 0);
  };

  const int nt = K / 32;                 // >= 3
  stage(0, 0);
  stage(1, 32);
  int cur = 0;
  for (int t = 0; t + 2 < nt; ++t) {
    asm volatile("s_waitcnt vmcnt(4)" ::: "memory");   // stage(t) landed
    __builtin_amdgcn_sched_barrier(0);
    __builtin_amdgcn_s_barrier();
    __builtin_amdgcn_sched_barrier(0);
    int nb = (cur == 0) ? 2 : cur - 1;                 // (cur+2)%3
    stage(nb, (t + 2) * 32);
    compute(cur);
    asm volatile("s_waitcnt lgkmcnt(0)" ::: "memory"); // pin ds_reads before next barrier
    __builtin_amdgcn_sched_barrier(0);
    cur = (cur == 2) ? 0 : cur + 1;
  }
  asm volatile("s_waitcnt vmcnt(4)" ::: "memory");
  __builtin_amdgcn_sched_barrier(0);
  __builtin_amdgcn_s_barrier();
  __builtin_amdgcn_sched_barrier(0);
  compute(cur);
  asm volatile("s_waitcnt lgkmcnt(0)" ::: "memory");
  __builtin_amdgcn_sched_barrier(0);
  cur = (cur == 2) ? 0 : cur + 1;
  asm volatile("s_waitcnt vmcnt(0)" ::: "memory");
  __builtin_amdgcn_sched_barrier(0);
  __builtin_amdgcn_s_barrier();
  __builtin_amdgcn_sched_barrier(0);
  compute(cur);

  #pragma unroll
  for (int mi = 0; mi < 4; mi++) {
    #pragma unroll
    for (int ni = 0; ni < 4; ni++) {
      int col = n0 + wc + ni * 16 + lr;
      if (OUTF == 0) {
        int sec = col >> 10;           // uniform per ni (16-col block in one section)
        #pragma unroll
        for (int j = 0; j < 4; j++) {
          int row = m0 + wr + mi * 16 + g * 4 + j;
          unsigned short ov = f2bf(acc[mi][ni][j]);
          if (sec == 1) {
            int b_ = row >> 11, s = row & 2047;
            int ck = col - 1024, h = ck >> 6, d = ck & 63;           // K -> Kswz
            Kswz[((size_t)(b_ * 16 + h) * 2048 + s) * 64 + (d ^ ((s & 7) << 3))] = ov;
          } else {
            Cb[(size_t)row * 3072 + col] = ov;                       // Q, V linear
          }
        }
      } else {
        #pragma unroll
        for (int j = 0; j < 4; j++) {
          int row = m0 + wr + mi * 16 + g * 4 + j;
          Cf[(size_t)row * N + col] = acc[mi][ni][j] + bias[col];
        }
      }
    }
  }
}

// ---------------- prep: V transpose into swizzled VTs --------------------
// VTswz[bh][d][s_hi*64 + (s_lo ^ ((d&7)<<3))]
__global__ __launch_bounds__(256) void prep_v(
    const unsigned short* __restrict__ QKV, unsigned short* __restrict__ VTs)
{
  __shared__ unsigned short vt[64 * 72];
  int bh = blockIdx.x;            // 64
  int st = blockIdx.y;            // 32
  int b = bh >> 4, h = bh & 15;
  int s0 = st * 64;
  int tid = threadIdx.x;
  #pragma unroll
  for (int i = 0; i < 2; i++) {
    int idx = tid + i * 256;      // 0..511
    int r = idx >> 3, gch = idx & 7;
    size_t rowg = (size_t)(b * 2048 + s0 + r) * 3072;
    short8 vv = *(const short8*)&QKV[rowg + 2048 + h * 64 + gch * 8];
    *(short8*)&vt[r * 72 + gch * 8] = vv;
  }
  __syncthreads();
  #pragma unroll
  for (int i = 0; i < 2; i++) {
    int idx = tid + i * 256;
    int d = idx >> 3, gp = idx & 7;
    int gs = gp ^ (d & 7);
    short8 o;
    #pragma unroll
    for (int j = 0; j < 8; j++) o[j] = (short)vt[(gs * 8 + j) * 72 + d];
    *(short8*)&VTs[(size_t)(bh * 64 + d) * 2048 + s0 + gp * 8] = o;
  }
}

// ---------------- flash attention, bf16, swapped QK^T (16x16) ------------
// grid: (64 bh, 8 q-blocks of 256); all q-blocks of one bh on one XCD.
__global__ __launch_bounds__(512, 4) void attn(
    const unsigned short* __restrict__ QKV,
    const unsigned short* __restrict__ Kswz,
    const unsigned short* __restrict__ VTs,
    unsigned short* __restrict__ O)
{
  __shared__ unsigned short smK[3][64 * 64];
  __shared__ unsigned short smV[3][64 * 64];
  __shared__ unsigned short smP[8][32 * 64];
  int bh = blockIdx.x, qb = blockIdx.y;
  int b = bh >> 4, h = bh & 15;
  int tid = threadIdx.x, w = tid >> 6, lane = tid & 63;
  int g = lane >> 4, lr = lane & 15;
  int q0 = qb * 256 + w * 32;
  const size_t kbse = (size_t)bh * 2048 * 64;
  const size_t vbse = (size_t)bh * 64 * 2048;
  const int srow8 = lane >> 3;
  const int sc8 = (lane & 7) * 8;

  auto stage = [&](int buf, int n0) {
    const unsigned short* gk = &Kswz[kbse + (size_t)(n0 + w * 8 + srow8) * 64 + sc8];
    __builtin_amdgcn_global_load_lds((gu32*)gk, (lu32*)&smK[buf][(w * 8) * 64], 16, 0, 0);
    const unsigned short* gv = &VTs[vbse + (size_t)(w * 8 + srow8) * 2048 + n0 + sc8];
    __builtin_amdgcn_global_load_lds((gu32*)gv, (lu32*)&smV[buf][(w * 8) * 64], 16, 0, 0);
  };

  const float SC = 0.125f * 1.44269504f;
  short8 bq[2][2];
  #pragma unroll
  for (int qf = 0; qf < 2; qf++)
    #pragma unroll
    for (int ks = 0; ks < 2; ks++) {
      short8 v = *(const short8*)&QKV[(size_t)(b * 2048 + q0 + qf * 16 + lr) * 3072 +
                                      h * 64 + ks * 32 + g * 8];
      #pragma unroll
      for (int j = 0; j < 4; j++) {
        float f0 = bf2f((unsigned short)v[2 * j]) * SC;
        float f1 = bf2f((unsigned short)v[2 * j + 1]) * SC;
        ((unsigned int*)&v)[j] = cvtpk(f0, f1);
      }
      bq[qf][ks] = v;
    }

  short8 vones;
  #pragma unroll
  for (int j = 0; j < 8; j++) vones[j] = (short)0x3F80;

  f32x4 acc_o[2][4] = {};
  f32x4 acc_l[2] = {};

  asm volatile("s_waitcnt vmcnt(0)" ::: "memory");
  __builtin_amdgcn_sched_barrier(0);
  stage(0, 0);
  stage(1, 64);

  auto compute = [&](int buf) {
    const unsigned short* K_ = smK[buf];
    const unsigned short* V_ = smV[buf];
    f32x4 s[4][2] = {};
    __builtin_amdgcn_s_setprio(1);
    #pragma unroll
    for (int nf = 0; nf < 4; nf++) {
      int row = nf * 16 + lr;
      #pragma unroll
      for (int ks = 0; ks < 2; ks++) {
        int eo = (ks * 64 + g * 16) ^ ((row & 7) << 4);
        short8 ak = *(const short8*)&K_[row * 64 + (eo >> 1)];
        #pragma unroll
        for (int qf = 0; qf < 2; qf++)
          s[nf][qf] = __builtin_amdgcn_mfma_f32_16x16x32_bf16(ak, bq[qf][ks], s[nf][qf], 0, 0, 0);
      }
    }
    __builtin_amdgcn_s_setprio(0);

    #pragma unroll
    for (int qf = 0; qf < 2; qf++) {
      int q = qf * 16 + lr;
      #pragma unroll
      for (int nf = 0; nf < 4; nf++) {
        float p0 = fexp2(s[nf][qf][0]);
        float p1 = fexp2(s[nf][qf][1]);
        float p2 = fexp2(s[nf][qf][2]);
        float p3 = fexp2(s[nf][qf][3]);
        uint2 pw;
        pw.x = cvtpk(p0, p1);
        pw.y = cvtpk(p2, p3);
        int eo = ((nf * 16 + g * 4) * 2) ^ ((q & 7) << 4);
        *(uint2*)&smP[w][q * 64 + (eo >> 1)] = pw;
      }
    }

    __builtin_amdgcn_s_setprio(1);
    #pragma unroll
    for (int ks = 0; ks < 2; ks++) {
      short8 ap[2];
      #pragma unroll
      for (int mq = 0; mq < 2; mq++) {
        int q = mq * 16 + lr;
        int eo = (ks * 64 + g * 16) ^ ((q & 7) << 4);
        ap[mq] = *(const short8*)&smP[w][q * 64 + (eo >> 1)];
        acc_l[mq] = __builtin_amdgcn_mfma_f32_16x16x32_bf16(ap[mq], vones, acc_l[mq], 0, 0, 0);
      }
      #pragma unroll
      for (int df = 0; df < 4; df++) {
        int d = df * 16 + lr;
        int eo = (ks * 64 + g * 16) ^ ((d & 7) << 4);
        short8 bv = *(const short8*)&V_[d * 64 + (eo >> 1)];
        #pragma unroll
        for (int mq = 0; mq < 2; mq++)
          acc_o[mq][df] = __builtin_amdgcn_mfma_f32_16x16x32_bf16(ap[mq], bv, acc_o[mq][df], 0, 0, 0);
      }
    }
    __builtin_amdgcn_s_setprio(0);
  };

  int cur = 0;
  for (int t = 0; t + 2 < 32; ++t) {
    asm volatile("s_waitcnt vmcnt(2)" ::: "memory");
    __builtin_amdgcn_sched_barrier(0);
    __builtin_amdgcn_s_barrier();
    __builtin_amdgcn_sched_barrier(0);
    int nb = (cur == 0) ? 2 : cur - 1;
    stage(nb, (t + 2) * 64);
    compute(cur);
    asm volatile("s_waitcnt lgkmcnt(0)" ::: "memory");
    __builtin_amdgcn_sched_barrier(0);
    cur = (cur == 2) ? 0 : cur + 1;
  }
  asm volatile("s_waitcnt vmcnt(2)" ::: "memory");
  __builtin_amdgcn_sched_barrier(0);
  __builtin_amdgcn_s_barrier();
  __builtin_amdgcn_sched_barrier(0);
  compute(cur);
  asm volatile("s_waitcnt lgkmcnt(0)" ::: "memory");
  __builtin_amdgcn_sched_barrier(0);
  cur = (cur == 2) ? 0 : cur + 1;
  asm volatile("s_waitcnt vmcnt(0)" ::: "memory");
  __builtin_amdgcn_sched_barrier(0);
  __builtin_amdgcn_s_barrier();
  __builtin_amdgcn_sched_barrier(0);
  compute(cur);

  #pragma unroll
  for (int mq = 0; mq < 2; mq++)
    #pragma unroll
    for (int j = 0; j < 4; j++) {
      float inv = 1.0f / acc_l[mq][j];
      #pragma unroll
      for (int df = 0; df < 4; df++) {
        int row = b * 2048 + q0 + mq * 16 + g * 4 + j;
        int col = h * 64 + df * 16 + lr;
        O[(size_t)row * 1024 + col] = f2bf(acc_o[mq][df][j] * inv);
      }
    }
}

// -------------------------------------------------------------------------
extern "C" void kernel_launch(void* const* d_in, const int* in_sizes, int n_in,
                              void* d_out, int out_size, void* d_ws, size_t ws_size,
                              hipStream_t stream) {
  const float* X  = (const float*)d_in[0];
  const float* Wq = (const float*)d_in[1];
  const float* Wk = (const float*)d_in[2];
  const float* Wv = (const float*)d_in[3];
  const float* Wo = (const float*)d_in[4];
  const float* bo = (const float*)d_in[5];
  const float* qd = (const float*)d_in[6];
  const float* qu = (const float*)d_in[7];
  const float* kd = (const float*)d_in[8];
  const float* ku = (const float*)d_in[9];
  const float* vd = (const float*)d_in[10];
  const float* vu = (const float*)d_in[11];
  const float* od = (const float*)d_in[12];
  const float* ou = (const float*)d_in[13];

  char* ws = (char*)d_ws;
  unsigned short* Wqkv = (unsigned short*)(ws);                       // 6,291,456 B
  unsigned short* Wob  = (unsigned short*)(ws + 6291456);             // 2,097,152 B
  unsigned short* Xb   = (unsigned short*)(ws + 8388608);             // 16,777,216 B (reused as attn out)
  unsigned short* QKV  = (unsigned short*)(ws + 25165824);            // 50,331,648 B (Q+V live)
  unsigned short* Kswz = (unsigned short*)(ws + 75497472);            // 16,777,216 B
  unsigned short* VTs  = (unsigned short*)(ws + 92274688);            // 16,777,216 B

  prep_in<<<12288, 256, 0, stream>>>(X, Xb, Wq, Wk, Wv, Wo, qd, qu, kd, ku,
                                     vd, vu, od, ou, Wqkv, Wob);
  // grid: x = m-tiles (64), y = n-tiles (24) -> per-XCD A-panel residency
  gemm_bt<0><<<dim3(64, 24), 256, 0, stream>>>(Xb, Wqkv, QKV, nullptr, nullptr,
                                               Kswz, 8192, 3072, 1024);
  prep_v<<<dim3(64, 32), 256, 0, stream>>>(QKV, VTs);
  attn<<<dim3(64, 8), 512, 0, stream>>>(QKV, Kswz, VTs, Xb);
  gemm_bt<1><<<dim3(64, 8), 256, 0, stream>>>(Xb, Wob, nullptr, (float*)d_out, bo,
                                              nullptr, 8192, 1024, 1024);
}

// Round 14
// 179.242 us; speedup vs baseline: 1.1030x; 1.0434x over previous
//
#include <hip/hip_runtime.h>
#include <stdint.h>

typedef __attribute__((ext_vector_type(8))) short short8;
typedef __attribute__((ext_vector_type(4))) float f32x4;

typedef const unsigned int __attribute__((address_space(1))) gu32;
typedef unsigned int __attribute__((address_space(3))) lu32;

__device__ __forceinline__ float bf2f(unsigned short u) {
  union { unsigned int i; float f; } v; v.i = ((unsigned int)u) << 16; return v.f;
}
__device__ __forceinline__ unsigned short f2bf(float f) {
  union { float f; unsigned int i; } v; v.f = f;
  unsigned int r = v.i + 0x7FFFu + ((v.i >> 16) & 1u);
  return (unsigned short)(r >> 16);
}
__device__ __forceinline__ float fexp2(float x) {
  float r; asm("v_exp_f32 %0, %1" : "=v"(r) : "v"(x)); return r;
}
__device__ __forceinline__ unsigned int cvtpk(float lo, float hi) {
  unsigned int r;
  asm("v_cvt_pk_bf16_f32 %0, %1, %2" : "=v"(r) : "v"(lo), "v"(hi));
  return r;
}

// ------- fused: cast X fp32->bf16 (blocks 0..8191) + fold LoRA (8192..) ---
__global__ __launch_bounds__(256) void prep_in(
    const float* __restrict__ X, unsigned short* __restrict__ Xb,
    const float* __restrict__ Wq, const float* __restrict__ Wk,
    const float* __restrict__ Wv, const float* __restrict__ Wo,
    const float* __restrict__ qd, const float* __restrict__ qu,
    const float* __restrict__ kd, const float* __restrict__ ku,
    const float* __restrict__ vd, const float* __restrict__ vu,
    const float* __restrict__ od, const float* __restrict__ ou,
    unsigned short* __restrict__ Wqkv, unsigned short* __restrict__ Wob)
{
  if (blockIdx.x < 8192) {
    int i = (blockIdx.x * 256 + threadIdx.x) * 4;
    float4 v = *(const float4*)&X[i];
    unsigned long long pk = (unsigned long long)f2bf(v.x) |
                            ((unsigned long long)f2bf(v.y) << 16) |
                            ((unsigned long long)f2bf(v.z) << 32) |
                            ((unsigned long long)f2bf(v.w) << 48);
    *(unsigned long long*)&Xb[i] = pk;
    return;
  }
  int idx = (blockIdx.x - 8192) * 256 + threadIdx.x;
  int sel = idx >> 18;
  int rem = (idx & 0x3FFFF) * 4;
  int o = rem >> 10, c = rem & 1023;
  const float *W, *up, *dn;
  if (sel == 0)      { W = Wq; up = qu; dn = qd; }
  else if (sel == 1) { W = Wk; up = ku; dn = kd; }
  else if (sel == 2) { W = Wv; up = vu; dn = vd; }
  else               { W = Wo; up = ou; dn = od; }
  float4 wv = *(const float4*)&W[rem];
  float a0 = wv.x, a1 = wv.y, a2 = wv.z, a3 = wv.w;
  #pragma unroll
  for (int r = 0; r < 4; r++) {
    float u = up[o * 4 + r];
    float4 dv = *(const float4*)&dn[r * 1024 + c];
    a0 += u * dv.x; a1 += u * dv.y; a2 += u * dv.z; a3 += u * dv.w;
  }
  unsigned long long pk = (unsigned long long)f2bf(a0) |
                          ((unsigned long long)f2bf(a1) << 16) |
                          ((unsigned long long)f2bf(a2) << 32) |
                          ((unsigned long long)f2bf(a3) << 48);
  if (sel < 3) *(unsigned long long*)&Wqkv[sel * 1048576 + rem] = pk;
  else         *(unsigned long long*)&Wob[rem] = pk;
}

// ---------------- bf16 GEMM, B^T input (C[m,n] = sum_k A[m,k]*B[n,k]) ----
// 128x128 tile, BK=32, 4 waves, 256 thr. 3-slot LDS rotation, counted
// vmcnt(4), vmcnt before barrier, lgkmcnt(0) read-pin. Grid x=m, y=n
// (per-XCD A-panel L2 residency, R13: FETCH 71.8->41MB).
// OUTF=0 (QKV): per-block routing: Q blocks (n0<1024) -> QKV linear;
// K blocks -> Kswz swizzled 2B scatter (within-row XOR, cheap);
// V blocks (n0>=2048) -> LDS transpose (staging LDS reused post-loop,
// prep_v's proven algebra) -> VTs contiguous 16B rows. V never touches QKV.
// OUTF=1: fp32 out + bias.
template <int OUTF>
__global__ __launch_bounds__(256) void gemm_bt(
    const unsigned short* __restrict__ A, const unsigned short* __restrict__ B,
    unsigned short* __restrict__ Cb, float* __restrict__ Cf,
    const float* __restrict__ bias, unsigned short* __restrict__ Kswz,
    unsigned short* __restrict__ VTs, int M, int N, int K)
{
  __shared__ unsigned short sm[24576];          // 48KB: 3xA(12288) + 3xB(12288)
  unsigned short* smA = sm;                     // [3][128*32]
  unsigned short* smB = sm + 12288;             // [3][128*32]
  const int tid = threadIdx.x;
  const int w = tid >> 6, lane = tid & 63;
  const int g = lane >> 4, lr = lane & 15;
  const int m0 = blockIdx.x * 128, n0 = blockIdx.y * 128;   // x=m, y=n
  const int srow = lane >> 2;
  const int scol = (lane & 3) * 8;
  const unsigned short* gA = A + (size_t)(m0 + w * 16 + srow) * K + scol;
  const unsigned short* gB = B + (size_t)(n0 + w * 16 + srow) * K + scol;
  f32x4 acc[4][4] = {};
  const int wr = (w >> 1) * 64, wc = (w & 1) * 64;

  auto stage = [&](int buf, int k0) {
    #pragma unroll
    for (int i = 0; i < 2; i++) {
      __builtin_amdgcn_global_load_lds((gu32*)(gA + (size_t)i * 64 * K + k0),
          (lu32*)&smA[buf * 4096 + (i * 64 + w * 16) * 32], 16, 0, 0);
      __builtin_amdgcn_global_load_lds((gu32*)(gB + (size_t)i * 64 * K + k0),
          (lu32*)&smB[buf * 4096 + (i * 64 + w * 16) * 32], 16, 0, 0);
    }
  };
  auto compute = [&](int buf) {
    short8 a[4], b[4];
    #pragma unroll
    for (int mi = 0; mi < 4; mi++) a[mi] = *(const short8*)&smA[buf * 4096 + (wr + mi * 16 + lr) * 32 + g * 8];
    #pragma unroll
    for (int ni = 0; ni < 4; ni++) b[ni] = *(const short8*)&smB[buf * 4096 + (wc + ni * 16 + lr) * 32 + g * 8];
    #pragma unroll
    for (int mi = 0; mi < 4; mi++)
      #pragma unroll
      for (int ni = 0; ni < 4; ni++)
        acc[mi][ni] = __builtin_amdgcn_mfma_f32_16x16x32_bf16(a[mi], b[ni], acc[mi][ni], 0, 0, 0);
  };

  const int nt = K / 32;                 // >= 3
  stage(0, 0);
  stage(1, 32);
  int cur = 0;
  for (int t = 0; t + 2 < nt; ++t) {
    asm volatile("s_waitcnt vmcnt(4)" ::: "memory");   // stage(t) landed
    __builtin_amdgcn_sched_barrier(0);
    __builtin_amdgcn_s_barrier();
    __builtin_amdgcn_sched_barrier(0);
    int nb = (cur == 0) ? 2 : cur - 1;                 // (cur+2)%3
    stage(nb, (t + 2) * 32);
    compute(cur);
    asm volatile("s_waitcnt lgkmcnt(0)" ::: "memory"); // pin ds_reads before next barrier
    __builtin_amdgcn_sched_barrier(0);
    cur = (cur == 2) ? 0 : cur + 1;
  }
  asm volatile("s_waitcnt vmcnt(4)" ::: "memory");
  __builtin_amdgcn_sched_barrier(0);
  __builtin_amdgcn_s_barrier();
  __builtin_amdgcn_sched_barrier(0);
  compute(cur);
  asm volatile("s_waitcnt lgkmcnt(0)" ::: "memory");
  __builtin_amdgcn_sched_barrier(0);
  cur = (cur == 2) ? 0 : cur + 1;
  asm volatile("s_waitcnt vmcnt(0)" ::: "memory");     // all stages landed
  __builtin_amdgcn_sched_barrier(0);
  __builtin_amdgcn_s_barrier();
  __builtin_amdgcn_sched_barrier(0);
  compute(cur);

  if (OUTF == 1) {
    #pragma unroll
    for (int mi = 0; mi < 4; mi++)
      #pragma unroll
      for (int ni = 0; ni < 4; ni++) {
        int col = n0 + wc + ni * 16 + lr;
        #pragma unroll
        for (int j = 0; j < 4; j++) {
          int row = m0 + wr + mi * 16 + g * 4 + j;
          Cf[(size_t)row * N + col] = acc[mi][ni][j] + bias[col];
        }
      }
    return;
  }

  if (n0 < 2048) {
    // Q (linear) or K (swizzled scatter within 128B rows)
    #pragma unroll
    for (int mi = 0; mi < 4; mi++)
      #pragma unroll
      for (int ni = 0; ni < 4; ni++) {
        int col = n0 + wc + ni * 16 + lr;
        #pragma unroll
        for (int j = 0; j < 4; j++) {
          int row = m0 + wr + mi * 16 + g * 4 + j;
          unsigned short ov = f2bf(acc[mi][ni][j]);
          if (n0 >= 1024) {
            int b_ = row >> 11, s = row & 2047;
            int ck = col - 1024, h = ck >> 6, d = ck & 63;
            Kswz[((size_t)(b_ * 16 + h) * 2048 + s) * 64 + (d ^ ((s & 7) << 3))] = ov;
          } else {
            Cb[(size_t)row * 3072 + col] = ov;
          }
        }
      }
    return;
  }

  // V block: LDS transpose (reuse staging LDS; all global_load_lds drained
  // by the final vmcnt(0) above) then contiguous 16B VTs rows.
  __syncthreads();                                   // all compute ds_reads done
  unsigned short* vbuf = sm;                         // [128][130] pad: bank-free cols
  #pragma unroll
  for (int mi = 0; mi < 4; mi++)
    #pragma unroll
    for (int ni = 0; ni < 4; ni++)
      #pragma unroll
      for (int j = 0; j < 4; j++) {
        int r = wr + mi * 16 + g * 4 + j;
        int c = wc + ni * 16 + lr;
        vbuf[r * 130 + c] = f2bf(acc[mi][ni][j]);
      }
  __syncthreads();
  {
    int b_ = m0 >> 11, s0g = m0 & 2047;
    int ck0 = n0 - 2048;
    int dd = tid >> 1, shalf = tid & 1;              // dd: tile col 0..127
    int d = dd & 63, h = (ck0 >> 6) + (dd >> 6);
    size_t rowbase = ((size_t)(b_ * 16 + h) * 64 + d) * 2048;
    #pragma unroll
    for (int gp = 0; gp < 8; gp++) {
      int gs = gp ^ (d & 7);
      short8 o;
      #pragma unroll
      for (int j = 0; j < 8; j++)
        o[j] = (short)vbuf[(shalf * 64 + gs * 8 + j) * 130 + dd];
      *(short8*)&VTs[rowbase + s0g + shalf * 64 + gp * 8] = o;
    }
  }
}

// ---------------- flash attention, bf16, swapped QK^T (16x16) ------------
// grid: (64 bh, 8 q-blocks of 256); all q-blocks of one bh on one XCD.
__global__ __launch_bounds__(512, 4) void attn(
    const unsigned short* __restrict__ QKV,
    const unsigned short* __restrict__ Kswz,
    const unsigned short* __restrict__ VTs,
    unsigned short* __restrict__ O)
{
  __shared__ unsigned short smK[3][64 * 64];
  __shared__ unsigned short smV[3][64 * 64];
  __shared__ unsigned short smP[8][32 * 64];
  int bh = blockIdx.x, qb = blockIdx.y;
  int b = bh >> 4, h = bh & 15;
  int tid = threadIdx.x, w = tid >> 6, lane = tid & 63;
  int g = lane >> 4, lr = lane & 15;
  int q0 = qb * 256 + w * 32;
  const size_t kbse = (size_t)bh * 2048 * 64;
  const size_t vbse = (size_t)bh * 64 * 2048;
  const int srow8 = lane >> 3;
  const int sc8 = (lane & 7) * 8;

  auto stage = [&](int buf, int n0) {
    const unsigned short* gk = &Kswz[kbse + (size_t)(n0 + w * 8 + srow8) * 64 + sc8];
    __builtin_amdgcn_global_load_lds((gu32*)gk, (lu32*)&smK[buf][(w * 8) * 64], 16, 0, 0);
    const unsigned short* gv = &VTs[vbse + (size_t)(w * 8 + srow8) * 2048 + n0 + sc8];
    __builtin_amdgcn_global_load_lds((gu32*)gv, (lu32*)&smV[buf][(w * 8) * 64], 16, 0, 0);
  };

  const float SC = 0.125f * 1.44269504f;
  short8 bq[2][2];
  #pragma unroll
  for (int qf = 0; qf < 2; qf++)
    #pragma unroll
    for (int ks = 0; ks < 2; ks++) {
      short8 v = *(const short8*)&QKV[(size_t)(b * 2048 + q0 + qf * 16 + lr) * 3072 +
                                      h * 64 + ks * 32 + g * 8];
      #pragma unroll
      for (int j = 0; j < 4; j++) {
        float f0 = bf2f((unsigned short)v[2 * j]) * SC;
        float f1 = bf2f((unsigned short)v[2 * j + 1]) * SC;
        ((unsigned int*)&v)[j] = cvtpk(f0, f1);
      }
      bq[qf][ks] = v;
    }

  short8 vones;
  #pragma unroll
  for (int j = 0; j < 8; j++) vones[j] = (short)0x3F80;

  f32x4 acc_o[2][4] = {};
  f32x4 acc_l[2] = {};

  asm volatile("s_waitcnt vmcnt(0)" ::: "memory");
  __builtin_amdgcn_sched_barrier(0);
  stage(0, 0);
  stage(1, 64);

  auto compute = [&](int buf) {
    const unsigned short* K_ = smK[buf];
    const unsigned short* V_ = smV[buf];
    f32x4 s[4][2] = {};
    __builtin_amdgcn_s_setprio(1);
    #pragma unroll
    for (int nf = 0; nf < 4; nf++) {
      int row = nf * 16 + lr;
      #pragma unroll
      for (int ks = 0; ks < 2; ks++) {
        int eo = (ks * 64 + g * 16) ^ ((row & 7) << 4);
        short8 ak = *(const short8*)&K_[row * 64 + (eo >> 1)];
        #pragma unroll
        for (int qf = 0; qf < 2; qf++)
          s[nf][qf] = __builtin_amdgcn_mfma_f32_16x16x32_bf16(ak, bq[qf][ks], s[nf][qf], 0, 0, 0);
      }
    }
    __builtin_amdgcn_s_setprio(0);

    #pragma unroll
    for (int qf = 0; qf < 2; qf++) {
      int q = qf * 16 + lr;
      #pragma unroll
      for (int nf = 0; nf < 4; nf++) {
        float p0 = fexp2(s[nf][qf][0]);
        float p1 = fexp2(s[nf][qf][1]);
        float p2 = fexp2(s[nf][qf][2]);
        float p3 = fexp2(s[nf][qf][3]);
        uint2 pw;
        pw.x = cvtpk(p0, p1);
        pw.y = cvtpk(p2, p3);
        int eo = ((nf * 16 + g * 4) * 2) ^ ((q & 7) << 4);
        *(uint2*)&smP[w][q * 64 + (eo >> 1)] = pw;
      }
    }

    __builtin_amdgcn_s_setprio(1);
    #pragma unroll
    for (int ks = 0; ks < 2; ks++) {
      short8 ap[2];
      #pragma unroll
      for (int mq = 0; mq < 2; mq++) {
        int q = mq * 16 + lr;
        int eo = (ks * 64 + g * 16) ^ ((q & 7) << 4);
        ap[mq] = *(const short8*)&smP[w][q * 64 + (eo >> 1)];
        acc_l[mq] = __builtin_amdgcn_mfma_f32_16x16x32_bf16(ap[mq], vones, acc_l[mq], 0, 0, 0);
      }
      #pragma unroll
      for (int df = 0; df < 4; df++) {
        int d = df * 16 + lr;
        int eo = (ks * 64 + g * 16) ^ ((d & 7) << 4);
        short8 bv = *(const short8*)&V_[d * 64 + (eo >> 1)];
        #pragma unroll
        for (int mq = 0; mq < 2; mq++)
          acc_o[mq][df] = __builtin_amdgcn_mfma_f32_16x16x32_bf16(ap[mq], bv, acc_o[mq][df], 0, 0, 0);
      }
    }
    __builtin_amdgcn_s_setprio(0);
  };

  int cur = 0;
  for (int t = 0; t + 2 < 32; ++t) {
    asm volatile("s_waitcnt vmcnt(2)" ::: "memory");
    __builtin_amdgcn_sched_barrier(0);
    __builtin_amdgcn_s_barrier();
    __builtin_amdgcn_sched_barrier(0);
    int nb = (cur == 0) ? 2 : cur - 1;
    stage(nb, (t + 2) * 64);
    compute(cur);
    asm volatile("s_waitcnt lgkmcnt(0)" ::: "memory");
    __builtin_amdgcn_sched_barrier(0);
    cur = (cur == 2) ? 0 : cur + 1;
  }
  asm volatile("s_waitcnt vmcnt(2)" ::: "memory");
  __builtin_amdgcn_sched_barrier(0);
  __builtin_amdgcn_s_barrier();
  __builtin_amdgcn_sched_barrier(0);
  compute(cur);
  asm volatile("s_waitcnt lgkmcnt(0)" ::: "memory");
  __builtin_amdgcn_sched_barrier(0);
  cur = (cur == 2) ? 0 : cur + 1;
  asm volatile("s_waitcnt vmcnt(0)" ::: "memory");
  __builtin_amdgcn_sched_barrier(0);
  __builtin_amdgcn_s_barrier();
  __builtin_amdgcn_sched_barrier(0);
  compute(cur);

  #pragma unroll
  for (int mq = 0; mq < 2; mq++)
    #pragma unroll
    for (int j = 0; j < 4; j++) {
      float inv = 1.0f / acc_l[mq][j];
      #pragma unroll
      for (int df = 0; df < 4; df++) {
        int row = b * 2048 + q0 + mq * 16 + g * 4 + j;
        int col = h * 64 + df * 16 + lr;
        O[(size_t)row * 1024 + col] = f2bf(acc_o[mq][df][j] * inv);
      }
    }
}

// -------------------------------------------------------------------------
extern "C" void kernel_launch(void* const* d_in, const int* in_sizes, int n_in,
                              void* d_out, int out_size, void* d_ws, size_t ws_size,
                              hipStream_t stream) {
  const float* X  = (const float*)d_in[0];
  const float* Wq = (const float*)d_in[1];
  const float* Wk = (const float*)d_in[2];
  const float* Wv = (const float*)d_in[3];
  const float* Wo = (const float*)d_in[4];
  const float* bo = (const float*)d_in[5];
  const float* qd = (const float*)d_in[6];
  const float* qu = (const float*)d_in[7];
  const float* kd = (const float*)d_in[8];
  const float* ku = (const float*)d_in[9];
  const float* vd = (const float*)d_in[10];
  const float* vu = (const float*)d_in[11];
  const float* od = (const float*)d_in[12];
  const float* ou = (const float*)d_in[13];

  char* ws = (char*)d_ws;
  unsigned short* Wqkv = (unsigned short*)(ws);                       // 6,291,456 B
  unsigned short* Wob  = (unsigned short*)(ws + 6291456);             // 2,097,152 B
  unsigned short* Xb   = (unsigned short*)(ws + 8388608);             // 16,777,216 B (reused as attn out)
  unsigned short* QKV  = (unsigned short*)(ws + 25165824);            // 50,331,648 B (Q live)
  unsigned short* Kswz = (unsigned short*)(ws + 75497472);            // 16,777,216 B
  unsigned short* VTs  = (unsigned short*)(ws + 92274688);            // 16,777,216 B

  prep_in<<<12288, 256, 0, stream>>>(X, Xb, Wq, Wk, Wv, Wo, qd, qu, kd, ku,
                                     vd, vu, od, ou, Wqkv, Wob);
  // grid: x = m-tiles (64), y = n-tiles (24) -> per-XCD A-panel residency
  gemm_bt<0><<<dim3(64, 24), 256, 0, stream>>>(Xb, Wqkv, QKV, nullptr, nullptr,
                                               Kswz, VTs, 8192, 3072, 1024);
  attn<<<dim3(64, 8), 512, 0, stream>>>(QKV, Kswz, VTs, Xb);
  gemm_bt<1><<<dim3(64, 8), 256, 0, stream>>>(Xb, Wob, nullptr, (float*)d_out, bo,
                                              nullptr, nullptr, 8192, 1024, 1024);
}